// Round 7
// baseline (248.085 us; speedup 1.0000x reference)
//
#include <hip/hip_runtime.h>
#include <hip/hip_bf16.h>

typedef __bf16 bf16;
typedef __bf16 bf16x8 __attribute__((ext_vector_type(8)));
typedef __bf16 bf16x4 __attribute__((ext_vector_type(4)));
typedef float f32x4 __attribute__((ext_vector_type(4)));
typedef float f32x2 __attribute__((ext_vector_type(2)));
typedef float f32x2u __attribute__((ext_vector_type(2))) __attribute__((aligned(4)));
typedef int  i32x4 __attribute__((ext_vector_type(4)));

#define MFMA16(a, b, c) __builtin_amdgcn_mfma_f32_16x16x32_bf16((a), (b), (c), 0, 0, 0)

// ---- ws layout (bytes) ----
static constexpr size_t FEATS_OFF = 0;                     // 4,194,304 bf16 = 8,388,608
static constexpr size_t OMW3_OFF  = 8388608;               // 995,328 bf16  = 1,990,656
static constexpr size_t DCWT_OFF  = OMW3_OFF + 1990656;    // 40,960 bf16   = 81,920
static constexpr size_t SC_OFF    = DCWT_OFF + 81920;      // 576 f32x4     = 9,216
static constexpr size_t PAD_OFF   = SC_OFF + 9216;         // 256*134*134 f32 = 18,386,944

// ---------------- prep kernels ----------------

// feat [b][cf][hh][px] f32 -> featS [b][hh][px][cf swizzled] bf16
__global__ void prep_featS(const float* __restrict__ feat, bf16* __restrict__ featS) {
    const int hh = blockIdx.x, b = blockIdx.y;
    __shared__ float t[64][129];
    for (int i = threadIdx.x; i < 64 * 32; i += 256) {
        int cf = i >> 5, q = i & 31;
        const float* src = feat + ((size_t)(b * 64 + cf) * 128 + hh) * 128 + q * 4;
        t[cf][q * 4 + 0] = src[0];
        t[cf][q * 4 + 1] = src[1];
        t[cf][q * 4 + 2] = src[2];
        t[cf][q * 4 + 3] = src[3];
    }
    __syncthreads();
    for (int i = threadIdx.x; i < 1024; i += 256) {
        int px = i >> 3, cfb = i & 7;
        int sb = cfb ^ (px & 7);
        bf16x8 v;
#pragma unroll
        for (int e = 0; e < 8; ++e) v[e] = (bf16)t[cfb * 8 + e][px];
        *(bf16x8*)(featS + ((size_t)((b * 128 + hh) * 128 + px) << 6) + sb * 8) = v;
    }
}

// omw3[ctile 36][kk 18][t 3][lane 64][j 8]
// dcwt (permuted-K GEMM2 A): [pair 5][wid 4][ot 4][lane 64][j 8]
//   k-slot s=(lane>>4)*8+j -> ck = pair*128 + wid*16 + (lane>>4)*4 + (j<4 ? j : j+60);
//   pair 4 (tail): j<4 -> ck = 512 + wid*16 + (lane>>4)*4 + j, j>=4 -> weight 0
// sconst: [pr*8 +{0,1}=ybias,{2,3}=xbias,{4,5}=mbias,{6,7}=coff bits]
__global__ void prep_weights(const float* __restrict__ om_w, const float* __restrict__ om_b,
                             const float* __restrict__ dc_w,
                             bf16* __restrict__ omw3, bf16* __restrict__ dcwt,
                             float* __restrict__ scf) {
    int i = blockIdx.x * 256 + threadIdx.x;
    if (i < 995328) {
        int e = i & 511, lane = e >> 3, j = e & 7;
        int q = i >> 9;
        int t = q % 3, q2 = q / 3, kk = q2 % 18, ct = q2 / 18;
        int ck = ct * 16 + (lane & 15);
        int kcol = kk * 32 + (lane >> 4) * 8 + j;
        int tap = kcol >> 6, cf = kcol & 63;
        int ch = (t < 2) ? (ck * 2 + t) : (1152 + ck);
        omw3[i] = (bf16)om_w[ch * 576 + cf * 9 + tap];
    }
    if (i < 40960) {
        int j = i & 7, lane = (i >> 3) & 63, ot = (i >> 9) & 3, wid = (i >> 11) & 3, pair = i >> 13;
        int o = ot * 16 + (lane & 15), gq = lane >> 4;
        float v = 0.f;
        if (pair < 4) {
            int ck = pair * 128 + wid * 16 + gq * 4 + ((j < 4) ? j : j + 60);
            v = dc_w[o * 576 + ck];
        } else if (j < 4) {
            int ck = 512 + wid * 16 + gq * 4 + j;
            v = dc_w[o * 576 + ck];
        }
        dcwt[i] = (bf16)v;
    }
    if (i < 576) {
        int ck = i;
        int c = ck / 9, kd = ck - 9 * c, kq = kd / 3, kx = kd - 3 * kq;
        int pr = ck >> 1, lo = ck & 1;
        scf[pr * 8 + 0 + lo] = om_b[ck * 2]     + (float)(kq + 2);
        scf[pr * 8 + 2 + lo] = om_b[ck * 2 + 1] + (float)(kx + 2);
        scf[pr * 8 + 4 + lo] = om_b[1152 + ck];
        scf[pr * 8 + 6 + lo] = __uint_as_float((unsigned)(c * 17956));
    }
}

// inputs [256][128][128] -> zero-padded pad [256][134][134] (3-px border)
__global__ void prep_pad(const float* __restrict__ inputs, float* __restrict__ pad) {
    int yy = blockIdx.x, bc = blockIdx.y, xx = threadIdx.x;
    if (xx >= 134) return;
    float v = 0.f;
    if (yy >= 3 && yy <= 130 && xx >= 3 && xx <= 130)
        v = inputs[(size_t)bc * 16384 + (yy - 3) * 128 + (xx - 3)];
    pad[((size_t)bc * 134 + yy) * 134 + xx] = v;
}

// ---------------- fused main kernel ----------------
// grid 1024 = (b,h,pxhalf); 4 waves = ck-quarters. ZERO main-loop barriers:
// per blk each wave does GEMM1 (16 cks x 3 x 64 px) -> sample -> p[4] regs;
// every 2 blks GEMM2 (permuted-K=32, full 64o x 64px partial, acc2=64 regs).
// Epilogue: 2-buffer parallel cross-wave reduce (3 barriers), bias+relu, store.

__global__ void __launch_bounds__(256, 3)
deform_fused(const float* __restrict__ pad,
             const bf16* __restrict__ featS,
             const bf16* __restrict__ omw3,
             const bf16* __restrict__ dcwt,
             const f32x4* __restrict__ sconst,
             const float* __restrict__ dcb,
             float* __restrict__ out)
{
    const int bid = blockIdx.x;
    const int P0 = (bid & 1) << 6;
    const int h = (bid >> 1) & 127;
    const int b = bid >> 8;
    const int tid = threadIdx.x;
    const int lane = tid & 63;
    const int wid_s = __builtin_amdgcn_readfirstlane(tid >> 6);
    const int l15 = lane & 15, g = lane >> 4;

    __shared__ __align__(16) unsigned char smem[33792];  // featB 25,344 / red 2x16,896
    char* featB = (char*)smem;

    // zero featB (halo cols / OOB rows stay 0)
    for (int i = tid; i < 6336; i += 256) ((unsigned*)featB)[i] = 0u;
    __syncthreads();
    // bulk-stage 3 rows x 65 px-cols x 128B from featS
    {
        const int s0 = (P0 == 0) ? 0 : 63;
        const int q0 = (P0 == 0) ? 1 : 0;
        for (int i = tid; i < 1560; i += 256) {
            int ky = i / 520, rem = i - ky * 520, row = rem >> 3, c = rem & 7;
            int hh = h - 1 + ky;
            if ((unsigned)hh < 128u) {
                const char* src = (const char*)featS
                    + (((size_t)(b * 128 + hh) * 128 + s0 + row) << 7) + c * 16;
                *(i32x4*)(featB + ((ky * 66 + q0 + row) << 7) + c * 16) = *(const i32x4*)src;
            }
        }
    }
    __syncthreads();

    // blk-invariant featB bases, folded: odd kk = even base ^ 64
    int fb9[9];
#pragma unroll
    for (int tap = 0; tap < 9; ++tap) {
        const int kyp = tap / 3, kxp = tap - 3 * kyp;
        const int q = l15 + kxp;
        fb9[tap] = (kyp * 66 + q) * 128 + ((g ^ ((q + 7) & 7)) << 4);
    }

    f32x4 acc2[4][4];
#pragma unroll
    for (int ot = 0; ot < 4; ++ot)
#pragma unroll
        for (int nf = 0; nf < 4; ++nf) acc2[ot][nf] = (f32x4){0.f, 0.f, 0.f, 0.f};

    const bf16* omw3_l = omw3 + lane * 8;
    const bf16* dcwt_l = dcwt + lane * 8;
    const float* padb0 = pad + (size_t)b * 64 * 17956;
    const f32x2 hb2 = {(float)h, (float)h};
    const f32x2 fx2 = {(float)(P0 + l15), (float)(P0 + l15)};
    const int g4 = g * 4;

    // GEMM1 + sample for one 64-ck block -> pdst[4] (this wave's 16 cks)
    auto do_block = [&](int blk, bf16x4* pdst) {
        f32x4 acc1[3][4];
#pragma unroll
        for (int t = 0; t < 3; ++t)
#pragma unroll
            for (int nf = 0; nf < 4; ++nf) acc1[t][nf] = (f32x4){0.f, 0.f, 0.f, 0.f};

        const int abase = (blk * 4 + wid_s) * 27648;

#pragma unroll
        for (int kk = 0; kk < 18; ++kk) {
            bf16x8 a0 = *(const bf16x8*)(omw3_l + abase + ((kk * 3 + 0) << 9));
            bf16x8 a1 = *(const bf16x8*)(omw3_l + abase + ((kk * 3 + 1) << 9));
            bf16x8 a2 = *(const bf16x8*)(omw3_l + abase + ((kk * 3 + 2) << 9));
            const int base = fb9[kk >> 1] ^ ((kk & 1) << 6);
            bf16x8 bfr[4];
#pragma unroll
            for (int nf = 0; nf < 4; ++nf)
                bfr[nf] = *(const bf16x8*)(featB + base + nf * 2048);
            __builtin_amdgcn_s_setprio(1);
#pragma unroll
            for (int nf = 0; nf < 4; ++nf) {
                acc1[0][nf] = MFMA16(a0, bfr[nf], acc1[0][nf]);
                acc1[1][nf] = MFMA16(a1, bfr[nf], acc1[1][nf]);
                acc1[2][nf] = MFMA16(a2, bfr[nf], acc1[2][nf]);
            }
            __builtin_amdgcn_s_setprio(0);
        }

        // per-blk sample constants (paired)
        const f32x4* scB = sconst + (blk * 64 + wid_s * 16);
        f32x4 e0A = scB[g4 + 0], e1A = scB[g4 + 1];
        f32x4 e0B = scB[g4 + 2], e1B = scB[g4 + 3];
        f32x2 yb[2], xb[2], mb[2];
        unsigned co[2][2];
        yb[0] = f32x2{e0A.x, e0A.y} + hb2;
        xb[0] = f32x2{e0A.z, e0A.w} + fx2;
        mb[0] = f32x2{e1A.x, e1A.y};
        co[0][0] = __float_as_uint(e1A.z); co[0][1] = __float_as_uint(e1A.w);
        yb[1] = f32x2{e0B.x, e0B.y} + hb2;
        xb[1] = f32x2{e0B.z, e0B.w} + fx2;
        mb[1] = f32x2{e1B.x, e1B.y};
        co[1][0] = __float_as_uint(e1B.z); co[1][1] = __float_as_uint(e1B.w);

#pragma unroll
        for (int nf = 0; nf < 4; ++nf) {
            float s[4];
#pragma unroll
            for (int pi = 0; pi < 2; ++pi) {
                f32x2 py = f32x2{acc1[0][nf][2 * pi], acc1[0][nf][2 * pi + 1]} + yb[pi];
                f32x2 px = f32x2{acc1[1][nf][2 * pi], acc1[1][nf][2 * pi + 1]} + xb[pi];
                f32x2 lg = f32x2{acc1[2][nf][2 * pi], acc1[2][nf][2 * pi + 1]} + mb[pi];
#pragma unroll
                for (int e = 0; e < 2; ++e) {
                    float pyc = __builtin_amdgcn_fmed3f(py[e], 0.5f, 132.5f);
                    float pxc = __builtin_amdgcn_fmed3f(px[e], 0.5f, 132.5f);
                    int y0 = (int)pyc, x0 = (int)pxc;       // trunc == floor (>0)
                    float wy = __builtin_amdgcn_fractf(pyc);
                    float wx = __builtin_amdgcn_fractf(pxc);
                    unsigned off = co[pi][e] + (unsigned)(y0 * 134 + x0);
                    f32x2u t0 = *(const f32x2u*)(padb0 + off);
                    f32x2u t1 = *(const f32x2u*)(padb0 + off + 134);
                    float top = t0.x + wx * (t0.y - t0.x);
                    float bot = t1.x + wx * (t1.y - t1.x);
                    float bil = top + wy * (bot - top);
                    float mk = __builtin_amdgcn_rcpf(1.f + __expf(-lg[e]));
                    s[2 * pi + e] = bil * mk;
                }
            }
            pdst[nf] = (bf16x4){(bf16)s[0], (bf16)s[1], (bf16)s[2], (bf16)s[3]};
            xb[0] += 16.f; xb[1] += 16.f;
        }
    };

    bf16x4 pE[4], pO[4];

#pragma unroll 1
    for (int pair = 0; pair < 4; ++pair) {
        do_block(2 * pair, pE);
        do_block(2 * pair + 1, pO);
        const bf16* aKb = dcwt_l + (((pair * 4 + wid_s) * 4) << 9);
        bf16x8 aK0 = *(const bf16x8*)(aKb);
        bf16x8 aK1 = *(const bf16x8*)(aKb + 512);
        bf16x8 aK2 = *(const bf16x8*)(aKb + 1024);
        bf16x8 aK3 = *(const bf16x8*)(aKb + 1536);
        __builtin_amdgcn_s_setprio(1);
#pragma unroll
        for (int nf = 0; nf < 4; ++nf) {
            bf16x8 bfr = __builtin_shufflevector(pE[nf], pO[nf], 0, 1, 2, 3, 4, 5, 6, 7);
            acc2[0][nf] = MFMA16(aK0, bfr, acc2[0][nf]);
            acc2[1][nf] = MFMA16(aK1, bfr, acc2[1][nf]);
            acc2[2][nf] = MFMA16(aK2, bfr, acc2[2][nf]);
            acc2[3][nf] = MFMA16(aK3, bfr, acc2[3][nf]);
        }
        __builtin_amdgcn_s_setprio(0);
    }
    // tail blk 8 (K=16 real + zero pad)
    do_block(8, pE);
    {
        const bf16 z = (bf16)0.f;
        bf16x4 zz = {z, z, z, z};
#pragma unroll
        for (int nf = 0; nf < 4; ++nf) pO[nf] = zz;
    }
    {
        const bf16* aKb = dcwt_l + (((4 * 4 + wid_s) * 4) << 9);
        bf16x8 aK0 = *(const bf16x8*)(aKb);
        bf16x8 aK1 = *(const bf16x8*)(aKb + 512);
        bf16x8 aK2 = *(const bf16x8*)(aKb + 1024);
        bf16x8 aK3 = *(const bf16x8*)(aKb + 1536);
#pragma unroll
        for (int nf = 0; nf < 4; ++nf) {
            bf16x8 bfr = __builtin_shufflevector(pE[nf], pO[nf], 0, 1, 2, 3, 4, 5, 6, 7);
            acc2[0][nf] = MFMA16(aK0, bfr, acc2[0][nf]);
            acc2[1][nf] = MFMA16(aK1, bfr, acc2[1][nf]);
            acc2[2][nf] = MFMA16(aK2, bfr, acc2[2][nf]);
            acc2[3][nf] = MFMA16(aK3, bfr, acc2[3][nf]);
        }
    }

    // ---- epilogue: 2-buffer parallel cross-wave reduce ----
    __syncthreads();
    float* red0 = (float*)smem;            // [64][66]
    float* red1 = (float*)smem + 4224;     // [64][66]
    float* mybuf = (wid_s & 1) ? red1 : red0;
    if (wid_s < 2) {
#pragma unroll
        for (int ot = 0; ot < 4; ++ot)
#pragma unroll
            for (int nf = 0; nf < 4; ++nf)
#pragma unroll
                for (int r = 0; r < 4; ++r)
                    mybuf[(ot * 16 + g * 4 + r) * 66 + nf * 16 + l15] = acc2[ot][nf][r];
    }
    __syncthreads();
    if (wid_s >= 2) {
#pragma unroll
        for (int ot = 0; ot < 4; ++ot)
#pragma unroll
            for (int nf = 0; nf < 4; ++nf)
#pragma unroll
                for (int r = 0; r < 4; ++r)
                    mybuf[(ot * 16 + g * 4 + r) * 66 + nf * 16 + l15] += acc2[ot][nf][r];
    }
    __syncthreads();
    for (int it = tid; it < 4096; it += 256) {
        int o = it >> 6, px = it & 63;
        float v = red0[o * 66 + px] + red1[o * 66 + px] + dcb[o];
        out[((size_t)(b * 64 + o) * 128 + h) * 128 + P0 + px] = fmaxf(v, 0.f);
    }
}

// ---------------- launcher ----------------
extern "C" void kernel_launch(void* const* d_in, const int* in_sizes, int n_in,
                              void* d_out, int out_size, void* d_ws, size_t ws_size,
                              hipStream_t stream) {
    const float* inputs = (const float*)d_in[0];
    const float* feat   = (const float*)d_in[1];
    const float* om_w   = (const float*)d_in[2];
    const float* om_b   = (const float*)d_in[3];
    const float* dc_w   = (const float*)d_in[4];
    const float* dc_b   = (const float*)d_in[5];
    float* out = (float*)d_out;

    char* ws = (char*)d_ws;
    bf16*  featS  = (bf16*)(ws + FEATS_OFF);
    bf16*  omw3   = (bf16*)(ws + OMW3_OFF);
    bf16*  dcwt   = (bf16*)(ws + DCWT_OFF);
    float* scf    = (float*)(ws + SC_OFF);
    float* pad    = (float*)(ws + PAD_OFF);

    prep_featS<<<dim3(128, 4), 256, 0, stream>>>(feat, featS);
    prep_weights<<<(995328 + 255) / 256, 256, 0, stream>>>(om_w, om_b, dc_w, omw3, dcwt, scf);
    prep_pad<<<dim3(134, 256), 256, 0, stream>>>(inputs, pad);

    deform_fused<<<1024, 256, 0, stream>>>(pad, featS, omw3, dcwt,
                                           (const f32x4*)scf, dc_b, out);
}

// Round 8
// 247.728 us; speedup vs baseline: 1.0014x; 1.0014x over previous
//
#include <hip/hip_runtime.h>
#include <hip/hip_bf16.h>

typedef __bf16 bf16;
typedef __bf16 bf16x8 __attribute__((ext_vector_type(8)));
typedef __bf16 bf16x4 __attribute__((ext_vector_type(4)));
typedef float f32x4 __attribute__((ext_vector_type(4)));
typedef float f32x2 __attribute__((ext_vector_type(2)));
typedef float f32x2u __attribute__((ext_vector_type(2))) __attribute__((aligned(4)));
typedef int  i32x4 __attribute__((ext_vector_type(4)));

#define MFMA16(a, b, c) __builtin_amdgcn_mfma_f32_16x16x32_bf16((a), (b), (c), 0, 0, 0)

// ---- ws layout (bytes) ----
static constexpr size_t FEATS_OFF = 0;                     // 4,194,304 bf16 = 8,388,608
static constexpr size_t OMW3_OFF  = 8388608;               // 995,328 bf16  = 1,990,656
static constexpr size_t DCWT_OFF  = OMW3_OFF + 1990656;    // 40,960 bf16   = 81,920
static constexpr size_t SC_OFF    = DCWT_OFF + 81920;      // 576 f32x4     = 9,216
static constexpr size_t PAD_OFF   = SC_OFF + 9216;         // 256*134*134 f32 = 18,386,944

// ---------------- prep kernels ----------------

// feat [b][cf][hh][px] f32 -> featS [b][hh][px][cf swizzled] bf16
__global__ void prep_featS(const float* __restrict__ feat, bf16* __restrict__ featS) {
    const int hh = blockIdx.x, b = blockIdx.y;
    __shared__ float t[64][129];
    for (int i = threadIdx.x; i < 64 * 32; i += 256) {
        int cf = i >> 5, q = i & 31;
        const float* src = feat + ((size_t)(b * 64 + cf) * 128 + hh) * 128 + q * 4;
        t[cf][q * 4 + 0] = src[0];
        t[cf][q * 4 + 1] = src[1];
        t[cf][q * 4 + 2] = src[2];
        t[cf][q * 4 + 3] = src[3];
    }
    __syncthreads();
    for (int i = threadIdx.x; i < 1024; i += 256) {
        int px = i >> 3, cfb = i & 7;
        int sb = cfb ^ (px & 7);
        bf16x8 v;
#pragma unroll
        for (int e = 0; e < 8; ++e) v[e] = (bf16)t[cfb * 8 + e][px];
        *(bf16x8*)(featS + ((size_t)((b * 128 + hh) * 128 + px) << 6) + sb * 8) = v;
    }
}

// omw3[ctile 36][kk 18][t 3][lane 64][j 8]
// dcwt (permuted-K GEMM2 A): [pair 5][wid 4][ot 4][lane 64][j 8]
// sconst: [pr*8 +{0,1}=ybias,{2,3}=xbias,{4,5}=mbias,{6,7}=coff bits]
__global__ void prep_weights(const float* __restrict__ om_w, const float* __restrict__ om_b,
                             const float* __restrict__ dc_w,
                             bf16* __restrict__ omw3, bf16* __restrict__ dcwt,
                             float* __restrict__ scf) {
    int i = blockIdx.x * 256 + threadIdx.x;
    if (i < 995328) {
        int e = i & 511, lane = e >> 3, j = e & 7;
        int q = i >> 9;
        int t = q % 3, q2 = q / 3, kk = q2 % 18, ct = q2 / 18;
        int ck = ct * 16 + (lane & 15);
        int kcol = kk * 32 + (lane >> 4) * 8 + j;
        int tap = kcol >> 6, cf = kcol & 63;
        int ch = (t < 2) ? (ck * 2 + t) : (1152 + ck);
        omw3[i] = (bf16)om_w[ch * 576 + cf * 9 + tap];
    }
    if (i < 40960) {
        int j = i & 7, lane = (i >> 3) & 63, ot = (i >> 9) & 3, wid = (i >> 11) & 3, pair = i >> 13;
        int o = ot * 16 + (lane & 15), gq = lane >> 4;
        float v = 0.f;
        if (pair < 4) {
            int ck = pair * 128 + wid * 16 + gq * 4 + ((j < 4) ? j : j + 60);
            v = dc_w[o * 576 + ck];
        } else if (j < 4) {
            int ck = 512 + wid * 16 + gq * 4 + j;
            v = dc_w[o * 576 + ck];
        }
        dcwt[i] = (bf16)v;
    }
    if (i < 576) {
        int ck = i;
        int c = ck / 9, kd = ck - 9 * c, kq = kd / 3, kx = kd - 3 * kq;
        int pr = ck >> 1, lo = ck & 1;
        scf[pr * 8 + 0 + lo] = om_b[ck * 2]     + (float)(kq + 2);
        scf[pr * 8 + 2 + lo] = om_b[ck * 2 + 1] + (float)(kx + 2);
        scf[pr * 8 + 4 + lo] = om_b[1152 + ck];
        scf[pr * 8 + 6 + lo] = __uint_as_float((unsigned)(c * 17956));
    }
}

// inputs [256][128][128] -> zero-padded pad [256][134][134] (3-px border)
__global__ void prep_pad(const float* __restrict__ inputs, float* __restrict__ pad) {
    int yy = blockIdx.x, bc = blockIdx.y, xx = threadIdx.x;
    if (xx >= 134) return;
    float v = 0.f;
    if (yy >= 3 && yy <= 130 && xx >= 3 && xx <= 130)
        v = inputs[(size_t)bc * 16384 + (yy - 3) * 128 + (xx - 3)];
    pad[((size_t)bc * 134 + yy) * 134 + xx] = v;
}

// ---------------- fused main kernel ----------------

struct S4 { bf16x4 v[4]; };   // one block's sampled fragments (value-returned: no alloca escape)

// GEMM1 (16 cks x 3 types x 64 px) + bilinear sample + mask for one 64-ck block.
__device__ __forceinline__ S4 do_block(
    int blk, int wid_s, int l15, int g,
    const char* __restrict__ featB, const int (&fb9)[9],
    const bf16* __restrict__ omw3_l, const f32x4* __restrict__ sconst,
    const float* __restrict__ padb0, f32x2 hb2, f32x2 fx2)
{
    f32x4 acc1[3][4];
#pragma unroll
    for (int t = 0; t < 3; ++t)
#pragma unroll
        for (int nf = 0; nf < 4; ++nf) acc1[t][nf] = (f32x4){0.f, 0.f, 0.f, 0.f};

    const int abase = (blk * 4 + wid_s) * 27648;

#pragma unroll
    for (int kk = 0; kk < 18; ++kk) {
        bf16x8 a0 = *(const bf16x8*)(omw3_l + abase + ((kk * 3 + 0) << 9));
        bf16x8 a1 = *(const bf16x8*)(omw3_l + abase + ((kk * 3 + 1) << 9));
        bf16x8 a2 = *(const bf16x8*)(omw3_l + abase + ((kk * 3 + 2) << 9));
        const int base = fb9[kk >> 1] ^ ((kk & 1) << 6);
        bf16x8 bfr[4];
#pragma unroll
        for (int nf = 0; nf < 4; ++nf)
            bfr[nf] = *(const bf16x8*)(featB + base + nf * 2048);
        __builtin_amdgcn_s_setprio(1);
#pragma unroll
        for (int nf = 0; nf < 4; ++nf) {
            acc1[0][nf] = MFMA16(a0, bfr[nf], acc1[0][nf]);
            acc1[1][nf] = MFMA16(a1, bfr[nf], acc1[1][nf]);
            acc1[2][nf] = MFMA16(a2, bfr[nf], acc1[2][nf]);
        }
        __builtin_amdgcn_s_setprio(0);
    }

    // per-blk sample constants (paired)
    const int g4 = g * 4;
    const f32x4* scB = sconst + (blk * 64 + wid_s * 16);
    f32x4 e0A = scB[g4 + 0], e1A = scB[g4 + 1];
    f32x4 e0B = scB[g4 + 2], e1B = scB[g4 + 3];
    f32x2 yb[2], xb[2], mb[2];
    unsigned co[2][2];
    yb[0] = f32x2{e0A.x, e0A.y} + hb2;
    xb[0] = f32x2{e0A.z, e0A.w} + fx2;
    mb[0] = f32x2{e1A.x, e1A.y};
    co[0][0] = __float_as_uint(e1A.z); co[0][1] = __float_as_uint(e1A.w);
    yb[1] = f32x2{e0B.x, e0B.y} + hb2;
    xb[1] = f32x2{e0B.z, e0B.w} + fx2;
    mb[1] = f32x2{e1B.x, e1B.y};
    co[1][0] = __float_as_uint(e1B.z); co[1][1] = __float_as_uint(e1B.w);

    S4 outp;
#pragma unroll
    for (int nf = 0; nf < 4; ++nf) {
        float s[4];
#pragma unroll
        for (int pi = 0; pi < 2; ++pi) {
            f32x2 py = f32x2{acc1[0][nf][2 * pi], acc1[0][nf][2 * pi + 1]} + yb[pi];
            f32x2 px = f32x2{acc1[1][nf][2 * pi], acc1[1][nf][2 * pi + 1]} + xb[pi];
            f32x2 lg = f32x2{acc1[2][nf][2 * pi], acc1[2][nf][2 * pi + 1]} + mb[pi];
#pragma unroll
            for (int e = 0; e < 2; ++e) {
                float pyc = __builtin_amdgcn_fmed3f(py[e], 0.5f, 132.5f);
                float pxc = __builtin_amdgcn_fmed3f(px[e], 0.5f, 132.5f);
                int y0 = (int)pyc, x0 = (int)pxc;       // trunc == floor (>0)
                float wy = __builtin_amdgcn_fractf(pyc);
                float wx = __builtin_amdgcn_fractf(pxc);
                unsigned off = co[pi][e] + (unsigned)(y0 * 134 + x0);
                f32x2u t0 = *(const f32x2u*)(padb0 + off);
                f32x2u t1 = *(const f32x2u*)(padb0 + off + 134);
                float top = t0.x + wx * (t0.y - t0.x);
                float bot = t1.x + wx * (t1.y - t1.x);
                float bil = top + wy * (bot - top);
                float mk = __builtin_amdgcn_rcpf(1.f + __expf(-lg[e]));
                s[2 * pi + e] = bil * mk;
            }
        }
        outp.v[nf] = (bf16x4){(bf16)s[0], (bf16)s[1], (bf16)s[2], (bf16)s[3]};
        xb[0] += 16.f; xb[1] += 16.f;
    }
    return outp;
}

// grid 1024 = (b,h,pxhalf); 4 waves = ck-quarters. ZERO main-loop barriers:
// per blk each wave: GEMM1 -> sample -> fragments in regs; every 2 blks GEMM2
// (permuted-K=32, full 64o x 64px partial, acc2=64 regs). Epilogue: 2-buffer
// parallel cross-wave reduce (3 barriers), bias+relu, store.

__global__ void __launch_bounds__(256, 3)
deform_fused(const float* __restrict__ pad,
             const bf16* __restrict__ featS,
             const bf16* __restrict__ omw3,
             const bf16* __restrict__ dcwt,
             const f32x4* __restrict__ sconst,
             const float* __restrict__ dcb,
             float* __restrict__ out)
{
    const int bid = blockIdx.x;
    const int P0 = (bid & 1) << 6;
    const int h = (bid >> 1) & 127;
    const int b = bid >> 8;
    const int tid = threadIdx.x;
    const int lane = tid & 63;
    const int wid_s = __builtin_amdgcn_readfirstlane(tid >> 6);
    const int l15 = lane & 15, g = lane >> 4;

    __shared__ __align__(16) unsigned char smem[33792];  // featB 25,344 / red 2x(64*66*4)
    char* featB = (char*)smem;

    // zero featB (halo cols / OOB rows stay 0)
    for (int i = tid; i < 6336; i += 256) ((unsigned*)featB)[i] = 0u;
    __syncthreads();
    // bulk-stage 3 rows x 65 px-cols x 128B from featS
    {
        const int s0 = (P0 == 0) ? 0 : 63;
        const int q0 = (P0 == 0) ? 1 : 0;
        for (int i = tid; i < 1560; i += 256) {
            int ky = i / 520, rem = i - ky * 520, row = rem >> 3, c = rem & 7;
            int hh = h - 1 + ky;
            if ((unsigned)hh < 128u) {
                const char* src = (const char*)featS
                    + (((size_t)(b * 128 + hh) * 128 + s0 + row) << 7) + c * 16;
                *(i32x4*)(featB + ((ky * 66 + q0 + row) << 7) + c * 16) = *(const i32x4*)src;
            }
        }
    }
    __syncthreads();

    // blk-invariant featB bases, folded: odd kk = even base ^ 64
    int fb9[9];
#pragma unroll
    for (int tap = 0; tap < 9; ++tap) {
        const int kyp = tap / 3, kxp = tap - 3 * kyp;
        const int q = l15 + kxp;
        fb9[tap] = (kyp * 66 + q) * 128 + ((g ^ ((q + 7) & 7)) << 4);
    }

    f32x4 acc2[4][4];
#pragma unroll
    for (int ot = 0; ot < 4; ++ot)
#pragma unroll
        for (int nf = 0; nf < 4; ++nf) acc2[ot][nf] = (f32x4){0.f, 0.f, 0.f, 0.f};

    const bf16* omw3_l = omw3 + lane * 8;
    const bf16* dcwt_l = dcwt + lane * 8;
    const float* padb0 = pad + (size_t)b * 64 * 17956;
    const f32x2 hb2 = {(float)h, (float)h};
    const f32x2 fx2 = {(float)(P0 + l15), (float)(P0 + l15)};

#pragma unroll 1
    for (int pair = 0; pair < 4; ++pair) {
        S4 pE = do_block(2 * pair,     wid_s, l15, g, featB, fb9, omw3_l, sconst, padb0, hb2, fx2);
        S4 pO = do_block(2 * pair + 1, wid_s, l15, g, featB, fb9, omw3_l, sconst, padb0, hb2, fx2);
        const bf16* aKb = dcwt_l + (((pair * 4 + wid_s) * 4) << 9);
        bf16x8 aK0 = *(const bf16x8*)(aKb);
        bf16x8 aK1 = *(const bf16x8*)(aKb + 512);
        bf16x8 aK2 = *(const bf16x8*)(aKb + 1024);
        bf16x8 aK3 = *(const bf16x8*)(aKb + 1536);
        __builtin_amdgcn_s_setprio(1);
#pragma unroll
        for (int nf = 0; nf < 4; ++nf) {
            bf16x8 bfr = __builtin_shufflevector(pE.v[nf], pO.v[nf], 0, 1, 2, 3, 4, 5, 6, 7);
            acc2[0][nf] = MFMA16(aK0, bfr, acc2[0][nf]);
            acc2[1][nf] = MFMA16(aK1, bfr, acc2[1][nf]);
            acc2[2][nf] = MFMA16(aK2, bfr, acc2[2][nf]);
            acc2[3][nf] = MFMA16(aK3, bfr, acc2[3][nf]);
        }
        __builtin_amdgcn_s_setprio(0);
    }
    // tail blk 8 (K=16 real + zero pad)
    {
        S4 pE = do_block(8, wid_s, l15, g, featB, fb9, omw3_l, sconst, padb0, hb2, fx2);
        const bf16 z = (bf16)0.f;
        bf16x4 zz = {z, z, z, z};
        const bf16* aKb = dcwt_l + (((4 * 4 + wid_s) * 4) << 9);
        bf16x8 aK0 = *(const bf16x8*)(aKb);
        bf16x8 aK1 = *(const bf16x8*)(aKb + 512);
        bf16x8 aK2 = *(const bf16x8*)(aKb + 1024);
        bf16x8 aK3 = *(const bf16x8*)(aKb + 1536);
#pragma unroll
        for (int nf = 0; nf < 4; ++nf) {
            bf16x8 bfr = __builtin_shufflevector(pE.v[nf], zz, 0, 1, 2, 3, 4, 5, 6, 7);
            acc2[0][nf] = MFMA16(aK0, bfr, acc2[0][nf]);
            acc2[1][nf] = MFMA16(aK1, bfr, acc2[1][nf]);
            acc2[2][nf] = MFMA16(aK2, bfr, acc2[2][nf]);
            acc2[3][nf] = MFMA16(aK3, bfr, acc2[3][nf]);
        }
    }

    // ---- epilogue: 2-buffer parallel cross-wave reduce ----
    __syncthreads();
    float* red0 = (float*)smem;            // [64][66]
    float* red1 = (float*)smem + 4224;     // [64][66]
    float* mybuf = (wid_s & 1) ? red1 : red0;
    if (wid_s < 2) {
#pragma unroll
        for (int ot = 0; ot < 4; ++ot)
#pragma unroll
            for (int nf = 0; nf < 4; ++nf)
#pragma unroll
                for (int r = 0; r < 4; ++r)
                    mybuf[(ot * 16 + g * 4 + r) * 66 + nf * 16 + l15] = acc2[ot][nf][r];
    }
    __syncthreads();
    if (wid_s >= 2) {
#pragma unroll
        for (int ot = 0; ot < 4; ++ot)
#pragma unroll
            for (int nf = 0; nf < 4; ++nf)
#pragma unroll
                for (int r = 0; r < 4; ++r)
                    mybuf[(ot * 16 + g * 4 + r) * 66 + nf * 16 + l15] += acc2[ot][nf][r];
    }
    __syncthreads();
    for (int it = tid; it < 4096; it += 256) {
        int o = it >> 6, px = it & 63;
        float v = red0[o * 66 + px] + red1[o * 66 + px] + dcb[o];
        out[((size_t)(b * 64 + o) * 128 + h) * 128 + P0 + px] = fmaxf(v, 0.f);
    }
}

// ---------------- launcher ----------------
extern "C" void kernel_launch(void* const* d_in, const int* in_sizes, int n_in,
                              void* d_out, int out_size, void* d_ws, size_t ws_size,
                              hipStream_t stream) {
    const float* inputs = (const float*)d_in[0];
    const float* feat   = (const float*)d_in[1];
    const float* om_w   = (const float*)d_in[2];
    const float* om_b   = (const float*)d_in[3];
    const float* dc_w   = (const float*)d_in[4];
    const float* dc_b   = (const float*)d_in[5];
    float* out = (float*)d_out;

    char* ws = (char*)d_ws;
    bf16*  featS  = (bf16*)(ws + FEATS_OFF);
    bf16*  omw3   = (bf16*)(ws + OMW3_OFF);
    bf16*  dcwt   = (bf16*)(ws + DCWT_OFF);
    float* scf    = (float*)(ws + SC_OFF);
    float* pad    = (float*)(ws + PAD_OFF);

    prep_featS<<<dim3(128, 4), 256, 0, stream>>>(feat, featS);
    prep_weights<<<(995328 + 255) / 256, 256, 0, stream>>>(om_w, om_b, dc_w, omw3, dcwt, scf);
    prep_pad<<<dim3(134, 256), 256, 0, stream>>>(inputs, pad);

    deform_fused<<<1024, 256, 0, stream>>>(pad, featS, omw3, dcwt,
                                           (const f32x4*)scf, dc_b, out);
}

// Round 9
// 247.045 us; speedup vs baseline: 1.0042x; 1.0028x over previous
//
#include <hip/hip_runtime.h>
#include <hip/hip_bf16.h>

typedef __bf16 bf16;
typedef __bf16 bf16x8 __attribute__((ext_vector_type(8)));
typedef __bf16 bf16x4 __attribute__((ext_vector_type(4)));
typedef float f32x4 __attribute__((ext_vector_type(4)));
typedef float f32x2 __attribute__((ext_vector_type(2)));
typedef float f32x2u __attribute__((ext_vector_type(2))) __attribute__((aligned(4)));
typedef int  i32x4 __attribute__((ext_vector_type(4)));

#define MFMA16(a, b, c) __builtin_amdgcn_mfma_f32_16x16x32_bf16((a), (b), (c), 0, 0, 0)

// ---- ws layout (bytes) ----
static constexpr size_t FEATS_OFF = 0;                     // 4,194,304 bf16 = 8,388,608
static constexpr size_t OMW3_OFF  = 8388608;               // 995,328 bf16  = 1,990,656
static constexpr size_t DCWT_OFF  = OMW3_OFF + 1990656;    // 40,960 bf16   = 81,920
static constexpr size_t SC_OFF    = DCWT_OFF + 81920;      // 576 f32x4     = 9,216
static constexpr size_t PAD_OFF   = SC_OFF + 9216;         // 256*134*134 f32 = 18,386,944

// ---------------- prep kernels ----------------

// feat [b][cf][hh][px] f32 -> featS [b][hh][px][cf swizzled] bf16
__global__ void prep_featS(const float* __restrict__ feat, bf16* __restrict__ featS) {
    const int hh = blockIdx.x, b = blockIdx.y;
    __shared__ float t[64][129];
    for (int i = threadIdx.x; i < 64 * 32; i += 256) {
        int cf = i >> 5, q = i & 31;
        const float* src = feat + ((size_t)(b * 64 + cf) * 128 + hh) * 128 + q * 4;
        t[cf][q * 4 + 0] = src[0];
        t[cf][q * 4 + 1] = src[1];
        t[cf][q * 4 + 2] = src[2];
        t[cf][q * 4 + 3] = src[3];
    }
    __syncthreads();
    for (int i = threadIdx.x; i < 1024; i += 256) {
        int px = i >> 3, cfb = i & 7;
        int sb = cfb ^ (px & 7);
        bf16x8 v;
#pragma unroll
        for (int e = 0; e < 8; ++e) v[e] = (bf16)t[cfb * 8 + e][px];
        *(bf16x8*)(featS + ((size_t)((b * 128 + hh) * 128 + px) << 6) + sb * 8) = v;
    }
}

// omw3[ctile 36][kk 18][t 3][lane 64][j 8]
// dcwt (permuted-K GEMM2 A): [pair 5][wid 4][ot 4][lane 64][j 8]
// sconst: [pr*8 +{0,1}=ybias,{2,3}=xbias,{4,5}=mbias,{6,7}=coff bits]
__global__ void prep_weights(const float* __restrict__ om_w, const float* __restrict__ om_b,
                             const float* __restrict__ dc_w,
                             bf16* __restrict__ omw3, bf16* __restrict__ dcwt,
                             float* __restrict__ scf) {
    int i = blockIdx.x * 256 + threadIdx.x;
    if (i < 995328) {
        int e = i & 511, lane = e >> 3, j = e & 7;
        int q = i >> 9;
        int t = q % 3, q2 = q / 3, kk = q2 % 18, ct = q2 / 18;
        int ck = ct * 16 + (lane & 15);
        int kcol = kk * 32 + (lane >> 4) * 8 + j;
        int tap = kcol >> 6, cf = kcol & 63;
        int ch = (t < 2) ? (ck * 2 + t) : (1152 + ck);
        omw3[i] = (bf16)om_w[ch * 576 + cf * 9 + tap];
    }
    if (i < 40960) {
        int j = i & 7, lane = (i >> 3) & 63, ot = (i >> 9) & 3, wid = (i >> 11) & 3, pair = i >> 13;
        int o = ot * 16 + (lane & 15), gq = lane >> 4;
        float v = 0.f;
        if (pair < 4) {
            int ck = pair * 128 + wid * 16 + gq * 4 + ((j < 4) ? j : j + 60);
            v = dc_w[o * 576 + ck];
        } else if (j < 4) {
            int ck = 512 + wid * 16 + gq * 4 + j;
            v = dc_w[o * 576 + ck];
        }
        dcwt[i] = (bf16)v;
    }
    if (i < 576) {
        int ck = i;
        int c = ck / 9, kd = ck - 9 * c, kq = kd / 3, kx = kd - 3 * kq;
        int pr = ck >> 1, lo = ck & 1;
        scf[pr * 8 + 0 + lo] = om_b[ck * 2]     + (float)(kq + 2);
        scf[pr * 8 + 2 + lo] = om_b[ck * 2 + 1] + (float)(kx + 2);
        scf[pr * 8 + 4 + lo] = om_b[1152 + ck];
        scf[pr * 8 + 6 + lo] = __uint_as_float((unsigned)(c * 17956));
    }
}

// inputs [256][128][128] -> zero-padded pad [256][134][134] (3-px border)
__global__ void prep_pad(const float* __restrict__ inputs, float* __restrict__ pad) {
    int yy = blockIdx.x, bc = blockIdx.y, xx = threadIdx.x;
    if (xx >= 134) return;
    float v = 0.f;
    if (yy >= 3 && yy <= 130 && xx >= 3 && xx <= 130)
        v = inputs[(size_t)bc * 16384 + (yy - 3) * 128 + (xx - 3)];
    pad[((size_t)bc * 134 + yy) * 134 + xx] = v;
}

// ---------------- fused main kernel ----------------

struct S4 { bf16x4 v[4]; };   // one block's sampled fragments (value-returned)

// GEMM1 (16 cks x 3 types x 64 px) + bilinear sample + mask for one 64-ck block.
__device__ __forceinline__ S4 do_block(
    int blk, int wid_s, int l15, int g,
    const char* __restrict__ featB, const int (&fb9)[9],
    const bf16* __restrict__ omw3_l, const f32x4* __restrict__ sconst,
    const float* __restrict__ padb0, f32x2 hb2, f32x2 fx2)
{
    f32x4 acc1[3][4];
#pragma unroll
    for (int t = 0; t < 3; ++t)
#pragma unroll
        for (int nf = 0; nf < 4; ++nf) acc1[t][nf] = (f32x4){0.f, 0.f, 0.f, 0.f};

    const int abase = (blk * 4 + wid_s) * 27648;

#pragma unroll
    for (int kk = 0; kk < 18; ++kk) {
        bf16x8 a0 = *(const bf16x8*)(omw3_l + abase + ((kk * 3 + 0) << 9));
        bf16x8 a1 = *(const bf16x8*)(omw3_l + abase + ((kk * 3 + 1) << 9));
        bf16x8 a2 = *(const bf16x8*)(omw3_l + abase + ((kk * 3 + 2) << 9));
        const int base = fb9[kk >> 1] ^ ((kk & 1) << 6);
        bf16x8 bfr[4];
#pragma unroll
        for (int nf = 0; nf < 4; ++nf)
            bfr[nf] = *(const bf16x8*)(featB + base + nf * 2048);
        __builtin_amdgcn_s_setprio(1);
#pragma unroll
        for (int nf = 0; nf < 4; ++nf) {
            acc1[0][nf] = MFMA16(a0, bfr[nf], acc1[0][nf]);
            acc1[1][nf] = MFMA16(a1, bfr[nf], acc1[1][nf]);
            acc1[2][nf] = MFMA16(a2, bfr[nf], acc1[2][nf]);
        }
        __builtin_amdgcn_s_setprio(0);
    }

    // per-blk sample constants (paired)
    const int g4 = g * 4;
    const f32x4* scB = sconst + (blk * 64 + wid_s * 16);
    f32x4 e0A = scB[g4 + 0], e1A = scB[g4 + 1];
    f32x4 e0B = scB[g4 + 2], e1B = scB[g4 + 3];
    f32x2 yb[2], xb[2], mb[2];
    unsigned co[2][2];
    yb[0] = f32x2{e0A.x, e0A.y} + hb2;
    xb[0] = f32x2{e0A.z, e0A.w} + fx2;
    mb[0] = f32x2{e1A.x, e1A.y};
    co[0][0] = __float_as_uint(e1A.z); co[0][1] = __float_as_uint(e1A.w);
    yb[1] = f32x2{e0B.x, e0B.y} + hb2;
    xb[1] = f32x2{e0B.z, e0B.w} + fx2;
    mb[1] = f32x2{e1B.x, e1B.y};
    co[1][0] = __float_as_uint(e1B.z); co[1][1] = __float_as_uint(e1B.w);

    S4 outp;
#pragma unroll
    for (int nf = 0; nf < 4; ++nf) {
        float s[4];
#pragma unroll
        for (int pi = 0; pi < 2; ++pi) {
            f32x2 py = f32x2{acc1[0][nf][2 * pi], acc1[0][nf][2 * pi + 1]} + yb[pi];
            f32x2 px = f32x2{acc1[1][nf][2 * pi], acc1[1][nf][2 * pi + 1]} + xb[pi];
            f32x2 lg = f32x2{acc1[2][nf][2 * pi], acc1[2][nf][2 * pi + 1]} + mb[pi];
#pragma unroll
            for (int e = 0; e < 2; ++e) {
                float pyc = __builtin_amdgcn_fmed3f(py[e], 0.5f, 132.5f);
                float pxc = __builtin_amdgcn_fmed3f(px[e], 0.5f, 132.5f);
                int y0 = (int)pyc, x0 = (int)pxc;       // trunc == floor (>0)
                float wy = __builtin_amdgcn_fractf(pyc);
                float wx = __builtin_amdgcn_fractf(pxc);
                unsigned off = co[pi][e] + (unsigned)(y0 * 134 + x0);
                f32x2u t0 = *(const f32x2u*)(padb0 + off);
                f32x2u t1 = *(const f32x2u*)(padb0 + off + 134);
                float top = t0.x + wx * (t0.y - t0.x);
                float bot = t1.x + wx * (t1.y - t1.x);
                float bil = top + wy * (bot - top);
                float mk = __builtin_amdgcn_rcpf(1.f + __expf(-lg[e]));
                s[2 * pi + e] = bil * mk;
            }
        }
        outp.v[nf] = (bf16x4){(bf16)s[0], (bf16)s[1], (bf16)s[2], (bf16)s[3]};
        xb[0] += 16.f; xb[1] += 16.f;
    }
    return outp;
}

// grid 1024 = (b,h,pxhalf); 4 waves = ck-quarters. ZERO main-loop barriers.
// amdgpu_waves_per_eu(3,3): pin occupancy to 3 waves/EU so the allocator
// gets the full 168-VGPR budget (R7/R8: it chose 84 regs + 182MB scratch).

__global__ void __launch_bounds__(256) __attribute__((amdgpu_waves_per_eu(3, 3)))
deform_fused(const float* __restrict__ pad,
             const bf16* __restrict__ featS,
             const bf16* __restrict__ omw3,
             const bf16* __restrict__ dcwt,
             const f32x4* __restrict__ sconst,
             const float* __restrict__ dcb,
             float* __restrict__ out)
{
    const int bid = blockIdx.x;
    const int P0 = (bid & 1) << 6;
    const int h = (bid >> 1) & 127;
    const int b = bid >> 8;
    const int tid = threadIdx.x;
    const int lane = tid & 63;
    const int wid_s = __builtin_amdgcn_readfirstlane(tid >> 6);
    const int l15 = lane & 15, g = lane >> 4;

    __shared__ __align__(16) unsigned char smem[33792];  // featB 25,344 / red 2x(64*66*4)
    char* featB = (char*)smem;

    // zero featB (halo cols / OOB rows stay 0)
    for (int i = tid; i < 6336; i += 256) ((unsigned*)featB)[i] = 0u;
    __syncthreads();
    // bulk-stage 3 rows x 65 px-cols x 128B from featS
    {
        const int s0 = (P0 == 0) ? 0 : 63;
        const int q0 = (P0 == 0) ? 1 : 0;
        for (int i = tid; i < 1560; i += 256) {
            int ky = i / 520, rem = i - ky * 520, row = rem >> 3, c = rem & 7;
            int hh = h - 1 + ky;
            if ((unsigned)hh < 128u) {
                const char* src = (const char*)featS
                    + (((size_t)(b * 128 + hh) * 128 + s0 + row) << 7) + c * 16;
                *(i32x4*)(featB + ((ky * 66 + q0 + row) << 7) + c * 16) = *(const i32x4*)src;
            }
        }
    }
    __syncthreads();

    // blk-invariant featB bases, folded: odd kk = even base ^ 64
    int fb9[9];
#pragma unroll
    for (int tap = 0; tap < 9; ++tap) {
        const int kyp = tap / 3, kxp = tap - 3 * kyp;
        const int q = l15 + kxp;
        fb9[tap] = (kyp * 66 + q) * 128 + ((g ^ ((q + 7) & 7)) << 4);
    }

    f32x4 acc2[4][4];
#pragma unroll
    for (int ot = 0; ot < 4; ++ot)
#pragma unroll
        for (int nf = 0; nf < 4; ++nf) acc2[ot][nf] = (f32x4){0.f, 0.f, 0.f, 0.f};

    const bf16* omw3_l = omw3 + lane * 8;
    const bf16* dcwt_l = dcwt + lane * 8;
    const float* padb0 = pad + (size_t)b * 64 * 17956;
    const f32x2 hb2 = {(float)h, (float)h};
    const f32x2 fx2 = {(float)(P0 + l15), (float)(P0 + l15)};

#pragma unroll 1
    for (int pair = 0; pair < 4; ++pair) {
        S4 pE = do_block(2 * pair,     wid_s, l15, g, featB, fb9, omw3_l, sconst, padb0, hb2, fx2);
        S4 pO = do_block(2 * pair + 1, wid_s, l15, g, featB, fb9, omw3_l, sconst, padb0, hb2, fx2);
        const bf16* aKb = dcwt_l + (((pair * 4 + wid_s) * 4) << 9);
        bf16x8 aK0 = *(const bf16x8*)(aKb);
        bf16x8 aK1 = *(const bf16x8*)(aKb + 512);
        bf16x8 aK2 = *(const bf16x8*)(aKb + 1024);
        bf16x8 aK3 = *(const bf16x8*)(aKb + 1536);
        __builtin_amdgcn_s_setprio(1);
#pragma unroll
        for (int nf = 0; nf < 4; ++nf) {
            bf16x8 bfr = __builtin_shufflevector(pE.v[nf], pO.v[nf], 0, 1, 2, 3, 4, 5, 6, 7);
            acc2[0][nf] = MFMA16(aK0, bfr, acc2[0][nf]);
            acc2[1][nf] = MFMA16(aK1, bfr, acc2[1][nf]);
            acc2[2][nf] = MFMA16(aK2, bfr, acc2[2][nf]);
            acc2[3][nf] = MFMA16(aK3, bfr, acc2[3][nf]);
        }
        __builtin_amdgcn_s_setprio(0);
    }
    // tail blk 8 (K=16 real + zero pad)
    {
        S4 pE = do_block(8, wid_s, l15, g, featB, fb9, omw3_l, sconst, padb0, hb2, fx2);
        const bf16 z = (bf16)0.f;
        bf16x4 zz = {z, z, z, z};
        const bf16* aKb = dcwt_l + (((4 * 4 + wid_s) * 4) << 9);
        bf16x8 aK0 = *(const bf16x8*)(aKb);
        bf16x8 aK1 = *(const bf16x8*)(aKb + 512);
        bf16x8 aK2 = *(const bf16x8*)(aKb + 1024);
        bf16x8 aK3 = *(const bf16x8*)(aKb + 1536);
#pragma unroll
        for (int nf = 0; nf < 4; ++nf) {
            bf16x8 bfr = __builtin_shufflevector(pE.v[nf], zz, 0, 1, 2, 3, 4, 5, 6, 7);
            acc2[0][nf] = MFMA16(aK0, bfr, acc2[0][nf]);
            acc2[1][nf] = MFMA16(aK1, bfr, acc2[1][nf]);
            acc2[2][nf] = MFMA16(aK2, bfr, acc2[2][nf]);
            acc2[3][nf] = MFMA16(aK3, bfr, acc2[3][nf]);
        }
    }

    // ---- epilogue: 2-buffer parallel cross-wave reduce ----
    __syncthreads();
    float* red0 = (float*)smem;            // [64][66]
    float* red1 = (float*)smem + 4224;     // [64][66]
    float* mybuf = (wid_s & 1) ? red1 : red0;
    if (wid_s < 2) {
#pragma unroll
        for (int ot = 0; ot < 4; ++ot)
#pragma unroll
            for (int nf = 0; nf < 4; ++nf)
#pragma unroll
                for (int r = 0; r < 4; ++r)
                    mybuf[(ot * 16 + g * 4 + r) * 66 + nf * 16 + l15] = acc2[ot][nf][r];
    }
    __syncthreads();
    if (wid_s >= 2) {
#pragma unroll
        for (int ot = 0; ot < 4; ++ot)
#pragma unroll
            for (int nf = 0; nf < 4; ++nf)
#pragma unroll
                for (int r = 0; r < 4; ++r)
                    mybuf[(ot * 16 + g * 4 + r) * 66 + nf * 16 + l15] += acc2[ot][nf][r];
    }
    __syncthreads();
    for (int it = tid; it < 4096; it += 256) {
        int o = it >> 6, px = it & 63;
        float v = red0[o * 66 + px] + red1[o * 66 + px] + dcb[o];
        out[((size_t)(b * 64 + o) * 128 + h) * 128 + P0 + px] = fmaxf(v, 0.f);
    }
}

// ---------------- launcher ----------------
extern "C" void kernel_launch(void* const* d_in, const int* in_sizes, int n_in,
                              void* d_out, int out_size, void* d_ws, size_t ws_size,
                              hipStream_t stream) {
    const float* inputs = (const float*)d_in[0];
    const float* feat   = (const float*)d_in[1];
    const float* om_w   = (const float*)d_in[2];
    const float* om_b   = (const float*)d_in[3];
    const float* dc_w   = (const float*)d_in[4];
    const float* dc_b   = (const float*)d_in[5];
    float* out = (float*)d_out;

    char* ws = (char*)d_ws;
    bf16*  featS  = (bf16*)(ws + FEATS_OFF);
    bf16*  omw3   = (bf16*)(ws + OMW3_OFF);
    bf16*  dcwt   = (bf16*)(ws + DCWT_OFF);
    float* scf    = (float*)(ws + SC_OFF);
    float* pad    = (float*)(ws + PAD_OFF);

    prep_featS<<<dim3(128, 4), 256, 0, stream>>>(feat, featS);
    prep_weights<<<(995328 + 255) / 256, 256, 0, stream>>>(om_w, om_b, dc_w, omw3, dcwt, scf);
    prep_pad<<<dim3(134, 256), 256, 0, stream>>>(inputs, pad);

    deform_fused<<<1024, 256, 0, stream>>>(pad, featS, omw3, dcwt,
                                           (const f32x4*)scf, dc_b, out);
}

// Round 10
// 185.617 us; speedup vs baseline: 1.3365x; 1.3309x over previous
//
#include <hip/hip_runtime.h>
#include <hip/hip_bf16.h>

typedef __bf16 bf16;
typedef __bf16 bf16x8 __attribute__((ext_vector_type(8)));
typedef __bf16 bf16x4 __attribute__((ext_vector_type(4)));
typedef float f32x4 __attribute__((ext_vector_type(4)));
typedef float f32x2 __attribute__((ext_vector_type(2)));
typedef float f32x2u __attribute__((ext_vector_type(2))) __attribute__((aligned(4)));
typedef int  i32x4 __attribute__((ext_vector_type(4)));

#define MFMA16(a, b, c) __builtin_amdgcn_mfma_f32_16x16x32_bf16((a), (b), (c), 0, 0, 0)

// ---- ws layout (bytes) ----
static constexpr size_t FEATS_OFF = 0;                    // featS: 4,194,304 bf16 = 8,388,608
static constexpr size_t OMW3_OFF  = 8388608;              // 995,328 bf16 = 1,990,656
static constexpr size_t DCW_OFF   = OMW3_OFF + 1990656;   // 36,864 bf16  = 73,728
static constexpr size_t SC_OFF    = DCW_OFF + 73728;      // 576 f32x4    = 9,216
static constexpr size_t PAD_OFF   = SC_OFF + 9216;        // 256*134*134 f32 = 18,386,944

// ---------------- prep kernels ----------------

// feat [b][cf][hh][px] f32 -> featS [b][hh][px][cf swizzled] bf16
__global__ void prep_featS(const float* __restrict__ feat, bf16* __restrict__ featS) {
    const int hh = blockIdx.x, b = blockIdx.y;
    __shared__ float t[64][129];
    for (int i = threadIdx.x; i < 64 * 32; i += 256) {
        int cf = i >> 5, q = i & 31;
        const float* src = feat + ((size_t)(b * 64 + cf) * 128 + hh) * 128 + q * 4;
        t[cf][q * 4 + 0] = src[0];
        t[cf][q * 4 + 1] = src[1];
        t[cf][q * 4 + 2] = src[2];
        t[cf][q * 4 + 3] = src[3];
    }
    __syncthreads();
    for (int i = threadIdx.x; i < 1024; i += 256) {
        int px = i >> 3, cfb = i & 7;
        int sb = cfb ^ (px & 7);
        bf16x8 v;
#pragma unroll
        for (int e = 0; e < 8; ++e) v[e] = (bf16)t[cfb * 8 + e][px];
        *(bf16x8*)(featS + ((size_t)((b * 128 + hh) * 128 + px) << 6) + sb * 8) = v;
    }
}

// omw3[ctile 36][kk 18][t 3][lane 64][j 8] ; dcw2p[win 18][ot 4][lane 64][j 8]
// sconst: [pr*8 +{0,1}=ybias,{2,3}=xbias,{4,5}=mbias,{6,7}=coff bits]
__global__ void prep_weights(const float* __restrict__ om_w, const float* __restrict__ om_b,
                             const float* __restrict__ dc_w,
                             bf16* __restrict__ omw3, bf16* __restrict__ dcw2p,
                             float* __restrict__ scf) {
    int i = blockIdx.x * 256 + threadIdx.x;
    if (i < 995328) {
        int e = i & 511, lane = e >> 3, j = e & 7;
        int q = i >> 9;
        int t = q % 3, q2 = q / 3, kk = q2 % 18, ct = q2 / 18;
        int ck = ct * 16 + (lane & 15);
        int kcol = kk * 32 + (lane >> 4) * 8 + j;
        int tap = kcol >> 6, cf = kcol & 63;
        int ch = (t < 2) ? (ck * 2 + t) : (1152 + ck);
        omw3[i] = (bf16)om_w[ch * 576 + cf * 9 + tap];
    }
    if (i < 36864) {
        int j = i & 7, lane = (i >> 3) & 63, ot = (i >> 9) & 3, win = i >> 11;
        int o = ot * 16 + (lane & 15);
        int ck = win * 32 + (lane >> 4) * 8 + j;
        dcw2p[i] = (bf16)dc_w[o * 576 + ck];
    }
    if (i < 576) {
        int ck = i;
        int c = ck / 9, kd = ck - 9 * c, kq = kd / 3, kx = kd - 3 * kq;
        int pr = ck >> 1, lo = ck & 1;
        scf[pr * 8 + 0 + lo] = om_b[ck * 2]     + (float)(kq + 2);
        scf[pr * 8 + 2 + lo] = om_b[ck * 2 + 1] + (float)(kx + 2);
        scf[pr * 8 + 4 + lo] = om_b[1152 + ck];
        scf[pr * 8 + 6 + lo] = __uint_as_float((unsigned)(c * 17956));
    }
}

// inputs [256][128][128] -> zero-padded pad [256][134][134] (3-px border)
__global__ void prep_pad(const float* __restrict__ inputs, float* __restrict__ pad) {
    int yy = blockIdx.x, bc = blockIdx.y, xx = threadIdx.x;
    if (xx >= 134) return;
    float v = 0.f;
    if (yy >= 3 && yy <= 130 && xx >= 3 && xx <= 130)
        v = inputs[(size_t)bc * 16384 + (yy - 3) * 128 + (xx - 3)];
    pad[((size_t)bc * 134 + yy) * 134 + xx] = v;
}

// ---------------- fused main kernel ----------------
// grid 1024 = (b,h,pxhalf); 4 waves = ck-quarters. Half-blk double-buffered
// exchange: every inter-barrier segment mixes MFMA with VALU/independent work:
//  segA: GEMM2-sh(blk-1) || GEMM1(blk) -> sample nf0-1 -> buf0 ; bar
//  segB: GEMM2-fh(blk)   || sample nf2-3 -> buf1        ; bar
// LDS: featB 25,344 + buf0 4,096 + buf1 4,096 (pad to 33,792) -> 4 wg/CU.

__global__ void __launch_bounds__(256, 4)
deform_fused(const float* __restrict__ pad,
             const bf16* __restrict__ featS,
             const bf16* __restrict__ omw3,
             const bf16* __restrict__ dcw2p,
             const f32x4* __restrict__ sconst,
             const float* __restrict__ dcb,
             float* __restrict__ out)
{
    const int bid = blockIdx.x;
    const int P0 = (bid & 1) << 6;
    const int h = (bid >> 1) & 127;
    const int b = bid >> 8;
    const int tid = threadIdx.x;
    const int lane = tid & 63;
    const int wid_s = __builtin_amdgcn_readfirstlane(tid >> 6);
    const int l15 = lane & 15, g = lane >> 4;

    __shared__ __align__(16) unsigned char smem[33792];
    char* featB = (char*)smem;            // [3 ky][66 q][128B]
    char* buf0  = (char*)smem + 25344;    // [32 px-rows][128B]
    char* buf1  = (char*)smem + 29440;    // [32 px-rows][128B]

    // zero featB (halo cols / OOB rows stay 0)
    for (int i = tid; i < 6336; i += 256) ((unsigned*)featB)[i] = 0u;
    __syncthreads();
    // bulk-stage 3 rows x 65 px-cols x 128B from featS
    {
        const int s0 = (P0 == 0) ? 0 : 63;
        const int q0 = (P0 == 0) ? 1 : 0;
        for (int i = tid; i < 1560; i += 256) {
            int ky = i / 520, rem = i - ky * 520, row = rem >> 3, c = rem & 7;
            int hh = h - 1 + ky;
            if ((unsigned)hh < 128u) {
                const char* src = (const char*)featS
                    + (((size_t)(b * 128 + hh) * 128 + s0 + row) << 7) + c * 16;
                *(i32x4*)(featB + ((ky * 66 + q0 + row) << 7) + c * 16) = *(const i32x4*)src;
            }
        }
    }
    __syncthreads();

    // blk-invariant featB bases: odd kk = even base ^ 64
    int fb9[9];
#pragma unroll
    for (int tap = 0; tap < 9; ++tap) {
        const int kyp = tap / 3, kxp = tap - 3 * kyp;
        const int q = l15 + kxp;
        fb9[tap] = (kyp * 66 + q) * 128 + ((g ^ ((q + 7) & 7)) << 4);
    }

    f32x4 acc2[4];
#pragma unroll
    for (int u = 0; u < 4; ++u) acc2[u] = (f32x4){0.f, 0.f, 0.f, 0.f};

    const bf16* omw3_l = omw3 + lane * 8;
    const bf16* dcw_l  = dcw2p + lane * 8;
    const float* padb0 = pad + (size_t)b * 64 * 17956;
    const f32x2 hb2 = {(float)h, (float)h};
    const f32x2 fx2 = {(float)(P0 + l15), (float)(P0 + l15)};
    const int g4 = g * 4;
    const int rswz = (g ^ (l15 & 7)) << 4;                       // GEMM2 read swizzle
    const int wswz = ((wid_s * 4 + g) ^ ((l15 & 7) << 1)) << 3;  // sample write swizzle

    bf16x8 aKp0, aKp1;   // carried GEMM2 A-frags (pending second half of blk-1)

#pragma unroll 1
    for (int blk = 0; blk < 9; ++blk) {
        // ---- segment A: pending GEMM2 second half (blk-1) ----
        if (blk > 0) {
            __builtin_amdgcn_s_setprio(1);
#pragma unroll
            for (int u = 2; u < 4; ++u) {
                const int rb = ((u - 2) * 16 + l15) * 128 + rswz;
                bf16x8 b0 = *(const bf16x8*)(buf1 + rb);
                bf16x8 b1 = *(const bf16x8*)(buf1 + (rb ^ 64));
                acc2[u] = MFMA16(aKp0, b0, acc2[u]);
                acc2[u] = MFMA16(aKp1, b1, acc2[u]);
            }
            __builtin_amdgcn_s_setprio(0);
        }

        // ---- GEMM1: this wave's 16 cks x 3 types x 64 px ----
        f32x4 acc1[3][4];
#pragma unroll
        for (int t = 0; t < 3; ++t)
#pragma unroll
            for (int nf = 0; nf < 4; ++nf) acc1[t][nf] = (f32x4){0.f, 0.f, 0.f, 0.f};

        const int abase = (blk * 4 + wid_s) * 27648;
#pragma unroll
        for (int kk = 0; kk < 18; ++kk) {
            bf16x8 a0 = *(const bf16x8*)(omw3_l + abase + ((kk * 3 + 0) << 9));
            bf16x8 a1 = *(const bf16x8*)(omw3_l + abase + ((kk * 3 + 1) << 9));
            bf16x8 a2 = *(const bf16x8*)(omw3_l + abase + ((kk * 3 + 2) << 9));
            const int base = fb9[kk >> 1] ^ ((kk & 1) << 6);
            bf16x8 bfr[4];
#pragma unroll
            for (int nf = 0; nf < 4; ++nf)
                bfr[nf] = *(const bf16x8*)(featB + base + nf * 2048);
            __builtin_amdgcn_s_setprio(1);
#pragma unroll
            for (int nf = 0; nf < 4; ++nf) {
                acc1[0][nf] = MFMA16(a0, bfr[nf], acc1[0][nf]);
                acc1[1][nf] = MFMA16(a1, bfr[nf], acc1[1][nf]);
                acc1[2][nf] = MFMA16(a2, bfr[nf], acc1[2][nf]);
            }
            __builtin_amdgcn_s_setprio(0);
        }

        // GEMM2 A-frags for this blk
        bf16x8 aK0 = *(const bf16x8*)(dcw_l + ((blk * 8 + wid_s) << 9));
        bf16x8 aK1 = *(const bf16x8*)(dcw_l + ((blk * 8 + 4 + wid_s) << 9));

        // per-blk sample constants (paired)
        const f32x4* scB = sconst + (blk * 64 + wid_s * 16);
        f32x4 e0A = scB[g4 + 0], e1A = scB[g4 + 1];
        f32x4 e0B = scB[g4 + 2], e1B = scB[g4 + 3];
        f32x2 yb[2], xb[2], mb[2];
        unsigned co[2][2];
        yb[0] = f32x2{e0A.x, e0A.y} + hb2;
        xb[0] = f32x2{e0A.z, e0A.w} + fx2;
        mb[0] = f32x2{e1A.x, e1A.y};
        co[0][0] = __float_as_uint(e1A.z); co[0][1] = __float_as_uint(e1A.w);
        yb[1] = f32x2{e0B.x, e0B.y} + hb2;
        xb[1] = f32x2{e0B.z, e0B.w} + fx2;
        mb[1] = f32x2{e1B.x, e1B.y};
        co[1][0] = __float_as_uint(e1B.z); co[1][1] = __float_as_uint(e1B.w);

        // ---- sample one nf tile -> dst buffer row (nf&1)*16+l15 ----
        auto sample_nf = [&](int nf, char* dst) {
            const f32x2 nfo = {16.f * (float)nf, 16.f * (float)nf};
            float s[4];
#pragma unroll
            for (int pi = 0; pi < 2; ++pi) {
                f32x2 py = f32x2{acc1[0][nf][2 * pi], acc1[0][nf][2 * pi + 1]} + yb[pi];
                f32x2 px = f32x2{acc1[1][nf][2 * pi], acc1[1][nf][2 * pi + 1]} + xb[pi] + nfo;
                f32x2 lg = f32x2{acc1[2][nf][2 * pi], acc1[2][nf][2 * pi + 1]} + mb[pi];
#pragma unroll
                for (int e = 0; e < 2; ++e) {
                    float pyc = __builtin_amdgcn_fmed3f(py[e], 0.5f, 132.5f);
                    float pxc = __builtin_amdgcn_fmed3f(px[e], 0.5f, 132.5f);
                    int y0 = (int)pyc, x0 = (int)pxc;      // trunc == floor (>0)
                    float wy = __builtin_amdgcn_fractf(pyc);
                    float wx = __builtin_amdgcn_fractf(pxc);
                    unsigned off = co[pi][e] + (unsigned)(y0 * 134 + x0);
                    f32x2u t0 = *(const f32x2u*)(padb0 + off);
                    f32x2u t1 = *(const f32x2u*)(padb0 + off + 134);
                    float top = t0.x + wx * (t0.y - t0.x);
                    float bot = t1.x + wx * (t1.y - t1.x);
                    float bil = top + wy * (bot - top);
                    float mk = __builtin_amdgcn_rcpf(1.f + __expf(-lg[e]));
                    s[2 * pi + e] = bil * mk;
                }
            }
            bf16x4 pk4 = {(bf16)s[0], (bf16)s[1], (bf16)s[2], (bf16)s[3]};
            *(bf16x4*)(dst + ((nf & 1) * 16 + l15) * 128 + wswz) = pk4;
        };

        // sample nf0,nf1 -> buf0
        sample_nf(0, buf0);
        sample_nf(1, buf0);
        __syncthreads();   // bar1: buf0 ready

        // ---- segment B: GEMM2 first half (u=0,1 from buf0) || sample nf2,nf3 ----
        __builtin_amdgcn_s_setprio(1);
#pragma unroll
        for (int u = 0; u < 2; ++u) {
            const int rb = (u * 16 + l15) * 128 + rswz;
            bf16x8 b0 = *(const bf16x8*)(buf0 + rb);
            bf16x8 b1 = *(const bf16x8*)(buf0 + (rb ^ 64));
            acc2[u] = MFMA16(aK0, b0, acc2[u]);
            acc2[u] = MFMA16(aK1, b1, acc2[u]);
        }
        __builtin_amdgcn_s_setprio(0);
        sample_nf(2, buf1);
        sample_nf(3, buf1);
        __syncthreads();   // bar2: buf1 ready

        aKp0 = aK0; aKp1 = aK1;
    }

    // ---- tail: pending GEMM2 second half for blk=8 ----
#pragma unroll
    for (int u = 2; u < 4; ++u) {
        const int rb = ((u - 2) * 16 + l15) * 128 + rswz;
        bf16x8 b0 = *(const bf16x8*)(buf1 + rb);
        bf16x8 b1 = *(const bf16x8*)(buf1 + (rb ^ 64));
        acc2[u] = MFMA16(aKp0, b0, acc2[u]);
        acc2[u] = MFMA16(aKp1, b1, acc2[u]);
    }

    // ---- epilogue: bias + relu, direct stores ----
    float bias[4];
#pragma unroll
    for (int r = 0; r < 4; ++r) bias[r] = dcb[wid_s * 16 + g * 4 + r];
#pragma unroll
    for (int u = 0; u < 4; ++u)
#pragma unroll
        for (int r = 0; r < 4; ++r) {
            int o = wid_s * 16 + g * 4 + r;
            out[((size_t)(b * 64 + o) * 128 + h) * 128 + P0 + u * 16 + l15]
                = fmaxf(acc2[u][r] + bias[r], 0.f);
        }
}

// ---------------- launcher ----------------
extern "C" void kernel_launch(void* const* d_in, const int* in_sizes, int n_in,
                              void* d_out, int out_size, void* d_ws, size_t ws_size,
                              hipStream_t stream) {
    const float* inputs = (const float*)d_in[0];
    const float* feat   = (const float*)d_in[1];
    const float* om_w   = (const float*)d_in[2];
    const float* om_b   = (const float*)d_in[3];
    const float* dc_w   = (const float*)d_in[4];
    const float* dc_b   = (const float*)d_in[5];
    float* out = (float*)d_out;

    char* ws = (char*)d_ws;
    bf16*  featS  = (bf16*)(ws + FEATS_OFF);
    bf16*  omw3   = (bf16*)(ws + OMW3_OFF);
    bf16*  dcw2p  = (bf16*)(ws + DCW_OFF);
    float* scf    = (float*)(ws + SC_OFF);
    float* pad    = (float*)(ws + PAD_OFF);

    prep_featS<<<dim3(128, 4), 256, 0, stream>>>(feat, featS);
    prep_weights<<<(995328 + 255) / 256, 256, 0, stream>>>(om_w, om_b, dc_w, omw3, dcw2p, scf);
    prep_pad<<<dim3(134, 256), 256, 0, stream>>>(inputs, pad);

    deform_fused<<<1024, 256, 0, stream>>>(pad, featS, omw3, dcw2p,
                                           (const f32x4*)scf, dc_b, out);
}